// Round 1
// baseline (592.544 us; speedup 1.0000x reference)
//
#include <hip/hip_runtime.h>
#include <cstdint>
#include <cstddef>

typedef __bf16 bf16_t;
typedef __bf16 bf16x8 __attribute__((ext_vector_type(8)));
typedef float  f32x4  __attribute__((ext_vector_type(4)));
typedef unsigned int uint32x4 __attribute__((ext_vector_type(4)));

#define DEV_INLINE __device__ __forceinline__

constexpr int Bsz = 4, Ssz = 2048, HID = 1024, FAC = 256, NH = 16, DKc = 64;
constexpr int Mrows = Bsz * Ssz; // 8192
constexpr float QSCALE = 0.18033688011112042f; // (1/sqrt(64)) * log2(e)

struct Ptr8 { const float* p[8]; };
struct Ptr3 { const float* p[3]; };

DEV_INLINE float fast_exp2(float x) {
#if __has_builtin(__builtin_amdgcn_exp2f)
  return __builtin_amdgcn_exp2f(x);
#else
  return exp2f(x);
#endif
}

// ---------------- weight transpose + cast: W[K,N] f32 -> Wt[N,K] bf16 ----------------
__global__ __launch_bounds__(256) void k_prep_w(Ptr8 s, bf16_t* wpt, bf16_t* wtt) {
  const int z = blockIdx.z;
  const int K = (z < 4) ? HID : FAC;
  const int N = (z < 4) ? FAC : HID;
  if ((int)(blockIdx.x * 32) >= N || (int)(blockIdx.y * 32) >= K) return;
  __shared__ float t[32][33];
  const float* src = s.p[z];
  bf16_t* dst = (z < 4) ? (wpt + (size_t)z * FAC * HID) : (wtt + (size_t)(z - 4) * FAC * HID);
  const int tx = threadIdx.x & 31, ty = threadIdx.x >> 5;
  const int kb = blockIdx.y * 32, nb = blockIdx.x * 32;
#pragma unroll
  for (int j = 0; j < 4; ++j)
    t[ty + j * 8][tx] = src[(size_t)(kb + ty + j * 8) * N + nb + tx];
  __syncthreads();
#pragma unroll
  for (int j = 0; j < 4; ++j)
    dst[(size_t)(nb + ty + j * 8) * K + kb + tx] = (bf16_t)t[tx][ty + j * 8];
}

// ---------------- bias pack: contiguous fp32 [4][256] proj and [4][1024] tran ----------------
__global__ __launch_bounds__(256) void k_pack_bias(Ptr8 s, float* bp, float* bt) {
  const int tid = threadIdx.x;
  for (int i = tid; i < 4 * FAC; i += 256) bp[i] = s.p[i >> 8][i & 255];
  for (int i = tid; i < 4 * HID; i += 256) bt[i] = s.p[4 + (i >> 10)][i & 1023];
}

// ---------------- cast fp32 -> bf16, 8 elements/thread ----------------
__global__ __launch_bounds__(256) void k_cast(Ptr3 s, bf16_t* dst) {
  const int z = blockIdx.z;
  const size_t base = ((size_t)blockIdx.x * 256 + threadIdx.x) * 8;
  const float* x = s.p[z] + base;
  f32x4 f0 = *(const f32x4*)x;
  f32x4 f1 = *(const f32x4*)(x + 4);
  union { bf16_t h[8]; uint32x4 u; } o;
#pragma unroll
  for (int j = 0; j < 4; ++j) { o.h[j] = (bf16_t)f0[j]; o.h[4 + j] = (bf16_t)f1[j]; }
  *(uint32x4*)(dst + (size_t)z * Mrows * HID + base) = o.u;
}

// ---------------- bf16 MFMA GEMM: C[M,N] = act(A[M,K] @ Bt[N,K]^T + bias) * scale ----------------
// 128x128 block tile, BK=32, 4 waves (2x2), 16x16x32 MFMA, 4x4 frags/wave.
template <int ACT, typename OUT_T>
__global__ __launch_bounds__(256) void k_gemm(const bf16_t* __restrict__ Aall,
                                              const bf16_t* __restrict__ Btall,
                                              const float* __restrict__ biasAll,
                                              OUT_T* __restrict__ Call,
                                              int N, int K,
                                              long long Az, long long Bz, long long Cz, int biasz,
                                              float sc0, float sc1, float sc2) {
  constexpr int LDT = 40; // lds row stride (bf16), padded
  __shared__ __align__(16) bf16_t As[128 * LDT];
  __shared__ __align__(16) bf16_t Bs[128 * LDT];

  const int z = blockIdx.z;
  const bf16_t* A = Aall + (size_t)z * Az;
  const bf16_t* Bt = Btall + (size_t)z * Bz;
  const float* bias = biasAll + (size_t)z * biasz;
  OUT_T* C = Call + (size_t)z * Cz;
  const float scale = (z == 0) ? sc0 : ((z == 1) ? sc1 : sc2);

  const int tid = threadIdx.x;
  const int lane = tid & 63, wave = tid >> 6;
  const int quad = lane >> 4, l16 = lane & 15;
  const int wr = wave >> 1, wc = wave & 1;
  const int m0 = blockIdx.y * 128, n0 = blockIdx.x * 128;

  const int srow = tid >> 2, sc8 = (tid & 3) * 8; // staging coords

  const bf16_t* ga0 = A + (size_t)(m0 + srow) * K + sc8;
  const bf16_t* gb0 = Bt + (size_t)(n0 + srow) * K + sc8;

  bf16_t* lA0 = As + srow * LDT + sc8;
  bf16_t* lA1 = As + (64 + srow) * LDT + sc8;
  bf16_t* lB0 = Bs + srow * LDT + sc8;
  bf16_t* lB1 = Bs + (64 + srow) * LDT + sc8;

  f32x4 acc[4][4] = {};

  for (int k0 = 0; k0 < K; k0 += 32) {
    uint32x4 va0 = *(const uint32x4*)(ga0 + k0);
    uint32x4 va1 = *(const uint32x4*)(ga0 + (size_t)64 * K + k0);
    uint32x4 vb0 = *(const uint32x4*)(gb0 + k0);
    uint32x4 vb1 = *(const uint32x4*)(gb0 + (size_t)64 * K + k0);
    *(uint32x4*)lA0 = va0;
    *(uint32x4*)lA1 = va1;
    *(uint32x4*)lB0 = vb0;
    *(uint32x4*)lB1 = vb1;
    __syncthreads();

    bf16x8 af[4], bfr[4];
#pragma unroll
    for (int i = 0; i < 4; ++i)
      af[i] = *(const bf16x8*)(As + (wr * 64 + i * 16 + l16) * LDT + quad * 8);
#pragma unroll
    for (int i = 0; i < 4; ++i)
      bfr[i] = *(const bf16x8*)(Bs + (wc * 64 + i * 16 + l16) * LDT + quad * 8);
#pragma unroll
    for (int mi = 0; mi < 4; ++mi)
#pragma unroll
      for (int ni = 0; ni < 4; ++ni)
        acc[mi][ni] = __builtin_amdgcn_mfma_f32_16x16x32_bf16(af[mi], bfr[ni], acc[mi][ni], 0, 0, 0);
    __syncthreads();
  }

#pragma unroll
  for (int mi = 0; mi < 4; ++mi) {
    const int rbase = m0 + wr * 64 + mi * 16 + quad * 4;
#pragma unroll
    for (int ni = 0; ni < 4; ++ni) {
      const int col = n0 + wc * 64 + ni * 16 + l16;
      const float bv = bias[col];
#pragma unroll
      for (int r = 0; r < 4; ++r) {
        float y = acc[mi][ni][r] + bv;
        if (ACT == 1) y = (y > 0.f) ? y : 0.2f * y;
        y *= scale;
        C[(size_t)(rbase + r) * N + col] = (OUT_T)y;
      }
    }
  }
}

// ---------------- flash attention (no-running-max softmax; scores are tiny, mask multiplicative) ----
// block: 256 thr = 4 waves, 64 q-rows per block, loop 64-key tiles.
// q is pre-scaled by (1/8)*log2(e) so p = exp2(score)*mask.
__global__ __launch_bounds__(256) void k_attn(const bf16_t* __restrict__ qkv,
                                              const int* __restrict__ mask,
                                              bf16_t* __restrict__ cv) {
  constexpr int LDA = 72;   // bf16 row stride
  constexpr int LSC = 68;   // f32 row stride for scores
  __shared__ __align__(16) bf16_t Qs[64 * LDA];
  __shared__ __align__(16) bf16_t Ks[64 * LDA];
  __shared__ __align__(16) bf16_t Vt[64 * LDA];
  __shared__ __align__(16) bf16_t Pb[64 * LDA];
  __shared__ __align__(16) float Sc[64 * LSC];
  __shared__ __align__(16) float mk[64];
  __shared__ float lsum[64];

  const int qt = blockIdx.x, h = blockIdx.y, b = blockIdx.z;
  const bf16_t* qp = qkv;
  const bf16_t* kp = qkv + (size_t)Mrows * HID;
  const bf16_t* vp = qkv + 2 * (size_t)Mrows * HID;

  const int tid = threadIdx.x;
  const int lane = tid & 63, wave = tid >> 6;
  const int quad = lane >> 4, l16 = lane & 15;
  const int sr = tid >> 3, sc8 = (tid & 7) * 8; // staging coords (rows 0..31 + 32)

  { // Q tile
    const size_t g0 = (size_t)(b * Ssz + qt * 64 + sr) * HID + h * DKc + sc8;
    *(uint32x4*)(Qs + sr * LDA + sc8) = *(const uint32x4*)(qp + g0);
    *(uint32x4*)(Qs + (sr + 32) * LDA + sc8) = *(const uint32x4*)(qp + g0 + (size_t)32 * HID);
  }
  if (tid < 64) lsum[tid] = 0.f;
  __syncthreads();

  const bf16x8 aq0 = *(const bf16x8*)(Qs + (wave * 16 + l16) * LDA + quad * 8);
  const bf16x8 aq1 = *(const bf16x8*)(Qs + (wave * 16 + l16) * LDA + 32 + quad * 8);

  f32x4 acc[4] = {};
  const int r4 = tid >> 2, g4 = tid & 3;

  for (int kt = 0; kt < 32; ++kt) {
    { // stage K tile, V^T tile, mask
      const size_t g0 = (size_t)(b * Ssz + kt * 64 + sr) * HID + h * DKc + sc8;
      *(uint32x4*)(Ks + sr * LDA + sc8) = *(const uint32x4*)(kp + g0);
      *(uint32x4*)(Ks + (sr + 32) * LDA + sc8) = *(const uint32x4*)(kp + g0 + (size_t)32 * HID);
      union { uint32x4 u; bf16_t e[8]; } v0, v1;
      v0.u = *(const uint32x4*)(vp + g0);
      v1.u = *(const uint32x4*)(vp + g0 + (size_t)32 * HID);
#pragma unroll
      for (int j = 0; j < 8; ++j) {
        Vt[(sc8 + j) * LDA + sr] = v0.e[j];
        Vt[(sc8 + j) * LDA + sr + 32] = v1.e[j];
      }
      if (tid < 64) mk[tid] = (mask[(size_t)b * Ssz + kt * 64 + tid] != 0) ? 1.f : 0.f;
    }
    __syncthreads();

    // QK^T -> Sc
#pragma unroll
    for (int ks = 0; ks < 4; ++ks) {
      bf16x8 b0 = *(const bf16x8*)(Ks + (ks * 16 + l16) * LDA + quad * 8);
      bf16x8 b1 = *(const bf16x8*)(Ks + (ks * 16 + l16) * LDA + 32 + quad * 8);
      f32x4 c = {};
      c = __builtin_amdgcn_mfma_f32_16x16x32_bf16(aq0, b0, c, 0, 0, 0);
      c = __builtin_amdgcn_mfma_f32_16x16x32_bf16(aq1, b1, c, 0, 0, 0);
#pragma unroll
      for (int r = 0; r < 4; ++r)
        Sc[(wave * 16 + quad * 4 + r) * LSC + ks * 16 + l16] = c[r];
    }
    __syncthreads();

    { // masked exp2 + row sums; write P (bf16)
      const float* sp = Sc + r4 * LSC + g4 * 16;
      const float* mp = mk + g4 * 16;
      union { bf16_t e[16]; uint32x4 u[2]; } pk;
      float psum = 0.f;
#pragma unroll
      for (int c4 = 0; c4 < 4; ++c4) {
        f32x4 sv = *(const f32x4*)(sp + c4 * 4);
        f32x4 mv = *(const f32x4*)(mp + c4 * 4);
#pragma unroll
        for (int j = 0; j < 4; ++j) {
          float p = fast_exp2(sv[j]) * mv[j];
          pk.e[c4 * 4 + j] = (bf16_t)p;
          psum += p;
        }
      }
      *(uint32x4*)(Pb + r4 * LDA + g4 * 16) = pk.u[0];
      *(uint32x4*)(Pb + r4 * LDA + g4 * 16 + 8) = pk.u[1];
      psum += __shfl_xor(psum, 1);
      psum += __shfl_xor(psum, 2);
      if (g4 == 0) lsum[r4] += psum;
    }
    __syncthreads();

    // P @ V
#pragma unroll
    for (int kk = 0; kk < 2; ++kk) {
      bf16x8 ap = *(const bf16x8*)(Pb + (wave * 16 + l16) * LDA + kk * 32 + quad * 8);
#pragma unroll
      for (int d = 0; d < 4; ++d) {
        bf16x8 bv = *(const bf16x8*)(Vt + (d * 16 + l16) * LDA + kk * 32 + quad * 8);
        acc[d] = __builtin_amdgcn_mfma_f32_16x16x32_bf16(ap, bv, acc[d], 0, 0, 0);
      }
    }
    __syncthreads();
  }

#pragma unroll
  for (int r = 0; r < 4; ++r) {
    const int row = wave * 16 + quad * 4 + r;
    const float rl = 1.f / lsum[row];
    const size_t o = (size_t)(b * Ssz + qt * 64 + row) * HID + h * DKc;
#pragma unroll
    for (int d = 0; d < 4; ++d)
      cv[o + d * 16 + l16] = (bf16_t)(acc[d][r] * rl);
  }
}

// ---------------- host ----------------
extern "C" void kernel_launch(void* const* d_in, const int* in_sizes, int n_in,
                              void* d_out, int out_size, void* d_ws, size_t ws_size,
                              hipStream_t stream) {
  (void)in_sizes; (void)n_in; (void)out_size; (void)ws_size;
  const float* q_in = (const float*)d_in[0];
  const float* k_in = (const float*)d_in[1];
  const float* v_in = (const float*)d_in[2];
  const int* mask = (const int*)d_in[3];

  // workspace layout (~84 MB)
  bf16_t* XB = (bf16_t*)d_ws;                          // 3 x [8192,1024] bf16 (cast in, later q/k/v)
  bf16_t* H3 = XB + (size_t)3 * Mrows * HID;           // 3 x [8192,256] bf16
  bf16_t* CV = H3 + (size_t)3 * Mrows * FAC;           // [8192,1024] bf16
  bf16_t* WPT = CV + (size_t)Mrows * HID;              // 4 x [256,1024] bf16 (proj W^T: q,k,v,o)
  bf16_t* WTT = WPT + (size_t)4 * FAC * HID;           // 4 x [1024,256] bf16 (tran W^T: q,k,v,o)
  float* BP = (float*)(WTT + (size_t)4 * FAC * HID);   // 4 x 256 f32
  float* BT = BP + 4 * FAC;                            // 4 x 1024 f32

  Ptr8 w;
  w.p[0] = (const float*)d_in[4];  w.p[1] = (const float*)d_in[8];
  w.p[2] = (const float*)d_in[12]; w.p[3] = (const float*)d_in[16];
  w.p[4] = (const float*)d_in[6];  w.p[5] = (const float*)d_in[10];
  w.p[6] = (const float*)d_in[14]; w.p[7] = (const float*)d_in[18];
  hipLaunchKernelGGL(k_prep_w, dim3(32, 32, 8), dim3(256), 0, stream, w, WPT, WTT);

  Ptr8 bs;
  bs.p[0] = (const float*)d_in[5];  bs.p[1] = (const float*)d_in[9];
  bs.p[2] = (const float*)d_in[13]; bs.p[3] = (const float*)d_in[17];
  bs.p[4] = (const float*)d_in[7];  bs.p[5] = (const float*)d_in[11];
  bs.p[6] = (const float*)d_in[15]; bs.p[7] = (const float*)d_in[19];
  hipLaunchKernelGGL(k_pack_bias, dim3(1), dim3(256), 0, stream, bs, BP, BT);

  Ptr3 xs; xs.p[0] = q_in; xs.p[1] = k_in; xs.p[2] = v_in;
  hipLaunchKernelGGL(k_cast, dim3(Mrows * HID / (256 * 8), 1, 3), dim3(256), 0, stream, xs, XB);

  // proj q,k,v: [8192,1024] @ [1024,256] + b -> leaky -> H3
  hipLaunchKernelGGL((k_gemm<1, bf16_t>), dim3(FAC / 128, Mrows / 128, 3), dim3(256), 0, stream,
                     XB, WPT, BP, H3, FAC, HID,
                     (long long)Mrows * HID, (long long)FAC * HID, (long long)Mrows * FAC, FAC,
                     1.f, 1.f, 1.f);

  // tran q,k,v: [8192,256] @ [256,1024] + b -> XB (q scaled by (1/8)*log2e)
  hipLaunchKernelGGL((k_gemm<0, bf16_t>), dim3(HID / 128, Mrows / 128, 3), dim3(256), 0, stream,
                     H3, WTT, BT, XB, HID, FAC,
                     (long long)Mrows * FAC, (long long)FAC * HID, (long long)Mrows * HID, HID,
                     QSCALE, 1.f, 1.f);

  // attention -> CV
  hipLaunchKernelGGL(k_attn, dim3(Ssz / 64, NH, Bsz), dim3(256), 0, stream, XB, mask, CV);

  // proj o: [8192,1024] @ [1024,256] + b -> leaky -> H3[0]
  hipLaunchKernelGGL((k_gemm<1, bf16_t>), dim3(FAC / 128, Mrows / 128, 1), dim3(256), 0, stream,
                     CV, WPT + (size_t)3 * FAC * HID, BP + 3 * FAC, H3, FAC, HID,
                     0LL, 0LL, 0LL, 0, 1.f, 1.f, 1.f);

  // tran o: [8192,256] @ [256,1024] + b -> d_out (fp32)
  hipLaunchKernelGGL((k_gemm<0, float>), dim3(HID / 128, Mrows / 128, 1), dim3(256), 0, stream,
                     H3, WTT + (size_t)3 * FAC * HID, BT + 3 * HID, (float*)d_out, HID, FAC,
                     0LL, 0LL, 0LL, 0, 1.f, 1.f, 1.f);
}

// Round 2
// 443.479 us; speedup vs baseline: 1.3361x; 1.3361x over previous
//
#include <hip/hip_runtime.h>
#include <cstdint>
#include <cstddef>

typedef __bf16 bf16_t;
typedef __bf16 bf16x8 __attribute__((ext_vector_type(8)));
typedef float  f32x4  __attribute__((ext_vector_type(4)));
typedef unsigned int uint32x4 __attribute__((ext_vector_type(4)));

#define DEV_INLINE __device__ __forceinline__

constexpr int Bsz = 4, Ssz = 2048, HID = 1024, FAC = 256, NH = 16, DKc = 64;
constexpr int Mrows = Bsz * Ssz; // 8192
constexpr float QSCALE = 0.18033688011112042f; // (1/sqrt(64)) * log2(e)

struct Ptr8 { const float* p[8]; };
struct Ptr3 { const float* p[3]; };

DEV_INLINE float fast_exp2(float x) {
#if __has_builtin(__builtin_amdgcn_exp2f)
  return __builtin_amdgcn_exp2f(x);
#else
  return exp2f(x);
#endif
}

// ---------------- weight transpose + cast: W[K,N] f32 -> Wt[N,K] bf16 ----------------
__global__ __launch_bounds__(256) void k_prep_w(Ptr8 s, bf16_t* wpt, bf16_t* wtt) {
  const int z = blockIdx.z;
  const int K = (z < 4) ? HID : FAC;
  const int N = (z < 4) ? FAC : HID;
  if ((int)(blockIdx.x * 32) >= N || (int)(blockIdx.y * 32) >= K) return;
  __shared__ float t[32][33];
  const float* src = s.p[z];
  bf16_t* dst = (z < 4) ? (wpt + (size_t)z * FAC * HID) : (wtt + (size_t)(z - 4) * FAC * HID);
  const int tx = threadIdx.x & 31, ty = threadIdx.x >> 5;
  const int kb = blockIdx.y * 32, nb = blockIdx.x * 32;
#pragma unroll
  for (int j = 0; j < 4; ++j)
    t[ty + j * 8][tx] = src[(size_t)(kb + ty + j * 8) * N + nb + tx];
  __syncthreads();
#pragma unroll
  for (int j = 0; j < 4; ++j)
    dst[(size_t)(nb + ty + j * 8) * K + kb + tx] = (bf16_t)t[tx][ty + j * 8];
}

// ---------------- bias pack + mask->float multiplier ----------------
__global__ __launch_bounds__(256) void k_pack_bias(Ptr8 s, const int* __restrict__ mask,
                                                   float* bp, float* bt, float* mf) {
  const int tid = threadIdx.x;
  for (int i = tid; i < 4 * FAC; i += 256) bp[i] = s.p[i >> 8][i & 255];
  for (int i = tid; i < 4 * HID; i += 256) bt[i] = s.p[4 + (i >> 10)][i & 1023];
  for (int i = tid; i < Bsz * Ssz; i += 256) mf[i] = (mask[i] != 0) ? 1.f : 0.f;
}

// ---------------- cast fp32 -> bf16, 8 elements/thread ----------------
__global__ __launch_bounds__(256) void k_cast(Ptr3 s, bf16_t* dst) {
  const int z = blockIdx.z;
  const size_t base = ((size_t)blockIdx.x * 256 + threadIdx.x) * 8;
  const float* x = s.p[z] + base;
  f32x4 f0 = *(const f32x4*)x;
  f32x4 f1 = *(const f32x4*)(x + 4);
  union { bf16_t h[8]; uint32x4 u; } o;
#pragma unroll
  for (int j = 0; j < 4; ++j) { o.h[j] = (bf16_t)f0[j]; o.h[4 + j] = (bf16_t)f1[j]; }
  *(uint32x4*)(dst + (size_t)z * Mrows * HID + base) = o.u;
}

// ---------------- V transpose: src[b*S+s][h*64+d] -> dst[(b*NH+h)*64+d][s] ----------------
__global__ __launch_bounds__(256) void k_tv(const bf16_t* __restrict__ src, bf16_t* __restrict__ dst) {
  constexpr int LDT = 72;
  __shared__ __align__(16) bf16_t T[64 * LDT];
  const int st = blockIdx.x, h = blockIdx.y, b = blockIdx.z;
  const int tid = threadIdx.x;
  const int sr = tid >> 3, sc8 = (tid & 7) * 8;
  const size_t g0 = (size_t)(b * Ssz + st * 64 + sr) * HID + h * DKc + sc8;
  *(uint32x4*)(T + sr * LDT + sc8) = *(const uint32x4*)(src + g0);
  *(uint32x4*)(T + (sr + 32) * LDT + sc8) = *(const uint32x4*)(src + g0 + (size_t)32 * HID);
  __syncthreads();
  union { bf16_t e[8]; uint32x4 u; } o0, o1;
#pragma unroll
  for (int j = 0; j < 8; ++j) {
    o0.e[j] = T[(sc8 + j) * LDT + sr];
    o1.e[j] = T[(sc8 + j) * LDT + sr + 32];
  }
  const size_t d0 = ((size_t)(b * NH + h) * DKc + sr) * Ssz + st * 64 + sc8;
  *(uint32x4*)(dst + d0) = o0.u;
  *(uint32x4*)(dst + d0 + (size_t)32 * Ssz) = o1.u;
}

// ---------------- bf16 MFMA GEMM: C[M,N] = act(A[M,K] @ Bt[N,K]^T + bias) * scale ----------------
template <int ACT, typename OUT_T>
__global__ __launch_bounds__(256) void k_gemm(const bf16_t* __restrict__ Aall,
                                              const bf16_t* __restrict__ Btall,
                                              const float* __restrict__ biasAll,
                                              OUT_T* __restrict__ Call,
                                              OUT_T* __restrict__ C2,
                                              int N, int K,
                                              long long Az, long long Bz, long long Cz, int biasz,
                                              float sc0, float sc1, float sc2) {
  constexpr int LDT = 40; // lds row stride (bf16), padded
  __shared__ __align__(16) bf16_t As[128 * LDT];
  __shared__ __align__(16) bf16_t Bs[128 * LDT];

  const int z = blockIdx.z;
  const bf16_t* A = Aall + (size_t)z * Az;
  const bf16_t* Bt = Btall + (size_t)z * Bz;
  const float* bias = biasAll + (size_t)z * biasz;
  OUT_T* C = (z == 2 && C2) ? C2 : (Call + (size_t)z * Cz);
  const float scale = (z == 0) ? sc0 : ((z == 1) ? sc1 : sc2);

  const int tid = threadIdx.x;
  const int lane = tid & 63, wave = tid >> 6;
  const int quad = lane >> 4, l16 = lane & 15;
  const int wr = wave >> 1, wc = wave & 1;
  const int m0 = blockIdx.y * 128, n0 = blockIdx.x * 128;

  const int srow = tid >> 2, sc8 = (tid & 3) * 8; // staging coords

  const bf16_t* ga0 = A + (size_t)(m0 + srow) * K + sc8;
  const bf16_t* gb0 = Bt + (size_t)(n0 + srow) * K + sc8;

  bf16_t* lA0 = As + srow * LDT + sc8;
  bf16_t* lA1 = As + (64 + srow) * LDT + sc8;
  bf16_t* lB0 = Bs + srow * LDT + sc8;
  bf16_t* lB1 = Bs + (64 + srow) * LDT + sc8;

  f32x4 acc[4][4] = {};

  for (int k0 = 0; k0 < K; k0 += 32) {
    uint32x4 va0 = *(const uint32x4*)(ga0 + k0);
    uint32x4 va1 = *(const uint32x4*)(ga0 + (size_t)64 * K + k0);
    uint32x4 vb0 = *(const uint32x4*)(gb0 + k0);
    uint32x4 vb1 = *(const uint32x4*)(gb0 + (size_t)64 * K + k0);
    *(uint32x4*)lA0 = va0;
    *(uint32x4*)lA1 = va1;
    *(uint32x4*)lB0 = vb0;
    *(uint32x4*)lB1 = vb1;
    __syncthreads();

    bf16x8 af[4], bfr[4];
#pragma unroll
    for (int i = 0; i < 4; ++i)
      af[i] = *(const bf16x8*)(As + (wr * 64 + i * 16 + l16) * LDT + quad * 8);
#pragma unroll
    for (int i = 0; i < 4; ++i)
      bfr[i] = *(const bf16x8*)(Bs + (wc * 64 + i * 16 + l16) * LDT + quad * 8);
#pragma unroll
    for (int mi = 0; mi < 4; ++mi)
#pragma unroll
      for (int ni = 0; ni < 4; ++ni)
        acc[mi][ni] = __builtin_amdgcn_mfma_f32_16x16x32_bf16(af[mi], bfr[ni], acc[mi][ni], 0, 0, 0);
    __syncthreads();
  }

#pragma unroll
  for (int mi = 0; mi < 4; ++mi) {
    const int rbase = m0 + wr * 64 + mi * 16 + quad * 4;
#pragma unroll
    for (int ni = 0; ni < 4; ++ni) {
      const int col = n0 + wc * 64 + ni * 16 + l16;
      const float bv = bias[col];
#pragma unroll
      for (int r = 0; r < 4; ++r) {
        float y = acc[mi][ni][r] + bv;
        if (ACT == 1) y = (y > 0.f) ? y : 0.2f * y;
        y *= scale;
        C[(size_t)(rbase + r) * N + col] = (OUT_T)y;
      }
    }
  }
}

// ---------------- flash attention v2 ----------------
// 64 q-rows/block, 4 waves. K/V double-buffered in LDS (1 sync/ktile), P wave-private,
// softmax fused on MFMA regs (no Sc LDS, no running max; psum in registers), V pre-transposed.
__global__ __launch_bounds__(256) void k_attn(const bf16_t* __restrict__ qkv,
                                              const float* __restrict__ maskf,
                                              bf16_t* __restrict__ cv) {
  constexpr int LDA = 72;
  __shared__ __align__(16) bf16_t Ks[2][64 * LDA];
  __shared__ __align__(16) bf16_t Vt[2][64 * LDA];
  __shared__ __align__(16) bf16_t Pb[64 * LDA];

  const int qt = blockIdx.x, h = blockIdx.y, b = blockIdx.z;
  const bf16_t* qp = qkv;
  const bf16_t* kp = qkv + (size_t)Mrows * HID;
  const bf16_t* vtp = qkv + 2 * (size_t)Mrows * HID + (size_t)(b * NH + h) * DKc * Ssz;

  const int tid = threadIdx.x;
  const int lane = tid & 63, wave = tid >> 6;
  const int quad = lane >> 4, l16 = lane & 15;
  const int sr = tid >> 3, sc8 = (tid & 7) * 8;

  // Q fragments direct from global (row = qt*64 + wave*16 + l16)
  const size_t qrow = (size_t)(b * Ssz + qt * 64 + wave * 16 + l16) * HID + h * DKc + quad * 8;
  const bf16x8 aq0 = *(const bf16x8*)(qp + qrow);
  const bf16x8 aq1 = *(const bf16x8*)(qp + qrow + 32);

  // staging pointers
  const bf16_t* kg0 = kp + (size_t)(b * Ssz + sr) * HID + h * DKc + sc8;
  const bf16_t* kg1 = kg0 + (size_t)32 * HID;
  const bf16_t* vg0 = vtp + (size_t)sr * Ssz + sc8;
  const bf16_t* vg1 = vg0 + (size_t)32 * Ssz;
  const float* mfp = maskf + b * Ssz + l16;

  // prologue: stage tile 0 into buffer 0
  {
    uint32x4 a = *(const uint32x4*)kg0;
    uint32x4 b2 = *(const uint32x4*)kg1;
    uint32x4 c = *(const uint32x4*)vg0;
    uint32x4 d = *(const uint32x4*)vg1;
    *(uint32x4*)(Ks[0] + sr * LDA + sc8) = a;
    *(uint32x4*)(Ks[0] + (sr + 32) * LDA + sc8) = b2;
    *(uint32x4*)(Vt[0] + sr * LDA + sc8) = c;
    *(uint32x4*)(Vt[0] + (sr + 32) * LDA + sc8) = d;
  }
  __syncthreads();

  f32x4 acc[4] = {};
  f32x4 psum = {};
  bf16_t* pbw = Pb + (wave * 16 + quad * 4) * LDA + l16; // wave-private P rows
  const bf16_t* pbr = Pb + (wave * 16 + l16) * LDA;

  for (int kt = 0; kt < 32; ++kt) {
    const int cur = kt & 1, nxt = cur ^ 1;
    // prefetch next K/V tile into registers (in flight during compute)
    const int ktn = (kt < 31) ? kt + 1 : 31;
    uint32x4 rk0 = *(const uint32x4*)(kg0 + (size_t)ktn * 64 * HID);
    uint32x4 rk1 = *(const uint32x4*)(kg1 + (size_t)ktn * 64 * HID);
    uint32x4 rv0 = *(const uint32x4*)(vg0 + ktn * 64);
    uint32x4 rv1 = *(const uint32x4*)(vg1 + ktn * 64);
    // mask multipliers for this tile's 64 key columns
    const float* mrow = mfp + kt * 64;
    const float mv[4] = { mrow[0], mrow[16], mrow[32], mrow[48] };

    // QK^T -> exp2*mask -> Pb (wave-private rows), psum in regs
#pragma unroll
    for (int ks = 0; ks < 4; ++ks) {
      bf16x8 b0 = *(const bf16x8*)(Ks[cur] + (ks * 16 + l16) * LDA + quad * 8);
      bf16x8 b1 = *(const bf16x8*)(Ks[cur] + (ks * 16 + l16) * LDA + 32 + quad * 8);
      f32x4 c = {};
      c = __builtin_amdgcn_mfma_f32_16x16x32_bf16(aq0, b0, c, 0, 0, 0);
      c = __builtin_amdgcn_mfma_f32_16x16x32_bf16(aq1, b1, c, 0, 0, 0);
#pragma unroll
      for (int r = 0; r < 4; ++r) {
        float p = fast_exp2(c[r]) * mv[ks];
        psum[r] += p;
        pbw[r * LDA + ks * 16] = (bf16_t)p;
      }
    }

    // P @ V (wave-private Pb rows; compiler inserts lgkmcnt waits, no barrier needed)
#pragma unroll
    for (int kk = 0; kk < 2; ++kk) {
      bf16x8 ap = *(const bf16x8*)(pbr + kk * 32 + quad * 8);
#pragma unroll
      for (int d = 0; d < 4; ++d) {
        bf16x8 bv = *(const bf16x8*)(Vt[cur] + (d * 16 + l16) * LDA + kk * 32 + quad * 8);
        acc[d] = __builtin_amdgcn_mfma_f32_16x16x32_bf16(ap, bv, acc[d], 0, 0, 0);
      }
    }

    // write prefetched tile into the other buffer
    *(uint32x4*)(Ks[nxt] + sr * LDA + sc8) = rk0;
    *(uint32x4*)(Ks[nxt] + (sr + 32) * LDA + sc8) = rk1;
    *(uint32x4*)(Vt[nxt] + sr * LDA + sc8) = rv0;
    *(uint32x4*)(Vt[nxt] + (sr + 32) * LDA + sc8) = rv1;
    __syncthreads(); // staging visible; everyone done with [cur]
  }

  // reduce row sums across the 16 lanes of each quad-row group
#pragma unroll
  for (int s = 1; s < 16; s <<= 1) {
    psum[0] += __shfl_xor(psum[0], s);
    psum[1] += __shfl_xor(psum[1], s);
    psum[2] += __shfl_xor(psum[2], s);
    psum[3] += __shfl_xor(psum[3], s);
  }

  const size_t obase = (size_t)(b * Ssz + qt * 64 + wave * 16 + quad * 4) * HID + h * DKc + l16;
#pragma unroll
  for (int r = 0; r < 4; ++r) {
    const float rl = 1.f / psum[r];
#pragma unroll
    for (int d = 0; d < 4; ++d)
      cv[obase + (size_t)r * HID + d * 16] = (bf16_t)(acc[d][r] * rl);
  }
}

// ---------------- host ----------------
extern "C" void kernel_launch(void* const* d_in, const int* in_sizes, int n_in,
                              void* d_out, int out_size, void* d_ws, size_t ws_size,
                              hipStream_t stream) {
  (void)in_sizes; (void)n_in; (void)out_size; (void)ws_size;
  const float* q_in = (const float*)d_in[0];
  const float* k_in = (const float*)d_in[1];
  const float* v_in = (const float*)d_in[2];
  const int* mask = (const int*)d_in[3];

  // workspace layout (~80 MB)
  bf16_t* XB = (bf16_t*)d_ws;                          // 3 x [8192,1024] bf16 (cast in -> later q, k, V^T)
  bf16_t* H3 = XB + (size_t)3 * Mrows * HID;           // 3 x [8192,256] bf16
  bf16_t* CV = H3 + (size_t)3 * Mrows * FAC;           // [8192,1024] bf16 (V staging, then attn out)
  bf16_t* WPT = CV + (size_t)Mrows * HID;              // 4 x [256,1024] bf16 (proj W^T: q,k,v,o)
  bf16_t* WTT = WPT + (size_t)4 * FAC * HID;           // 4 x [1024,256] bf16 (tran W^T: q,k,v,o)
  float* BP = (float*)(WTT + (size_t)4 * FAC * HID);   // 4 x 256 f32
  float* BT = BP + 4 * FAC;                            // 4 x 1024 f32
  float* MF = BT + 4 * HID;                            // [4,2048] f32 mask multiplier
  bf16_t* VTg = XB + 2 * (size_t)Mrows * HID;          // V^T target (reuses XB v-slot)

  Ptr8 w;
  w.p[0] = (const float*)d_in[4];  w.p[1] = (const float*)d_in[8];
  w.p[2] = (const float*)d_in[12]; w.p[3] = (const float*)d_in[16];
  w.p[4] = (const float*)d_in[6];  w.p[5] = (const float*)d_in[10];
  w.p[6] = (const float*)d_in[14]; w.p[7] = (const float*)d_in[18];
  hipLaunchKernelGGL(k_prep_w, dim3(32, 32, 8), dim3(256), 0, stream, w, WPT, WTT);

  Ptr8 bs;
  bs.p[0] = (const float*)d_in[5];  bs.p[1] = (const float*)d_in[9];
  bs.p[2] = (const float*)d_in[13]; bs.p[3] = (const float*)d_in[17];
  bs.p[4] = (const float*)d_in[7];  bs.p[5] = (const float*)d_in[11];
  bs.p[6] = (const float*)d_in[15]; bs.p[7] = (const float*)d_in[19];
  hipLaunchKernelGGL(k_pack_bias, dim3(1), dim3(256), 0, stream, bs, mask, BP, BT, MF);

  Ptr3 xs; xs.p[0] = q_in; xs.p[1] = k_in; xs.p[2] = v_in;
  hipLaunchKernelGGL(k_cast, dim3(Mrows * HID / (256 * 8), 1, 3), dim3(256), 0, stream, xs, XB);

  // proj q,k,v: [8192,1024] @ [1024,256] + b -> leaky -> H3
  hipLaunchKernelGGL((k_gemm<1, bf16_t>), dim3(FAC / 128, Mrows / 128, 3), dim3(256), 0, stream,
                     XB, WPT, BP, H3, (bf16_t*)nullptr, FAC, HID,
                     (long long)Mrows * HID, (long long)FAC * HID, (long long)Mrows * FAC, FAC,
                     1.f, 1.f, 1.f);

  // tran q,k,v: [8192,256] @ [256,1024] + b -> q,k into XB; v into CV (scratch)
  hipLaunchKernelGGL((k_gemm<0, bf16_t>), dim3(HID / 128, Mrows / 128, 3), dim3(256), 0, stream,
                     H3, WTT, BT, XB, CV, HID, FAC,
                     (long long)Mrows * FAC, (long long)FAC * HID, (long long)Mrows * HID, HID,
                     QSCALE, 1.f, 1.f);

  // transpose V: CV -> VTg ([b,h,d,s])
  hipLaunchKernelGGL(k_tv, dim3(Ssz / 64, NH, Bsz), dim3(256), 0, stream, CV, VTg);

  // attention -> CV
  hipLaunchKernelGGL(k_attn, dim3(Ssz / 64, NH, Bsz), dim3(256), 0, stream, XB, MF, CV);

  // proj o: [8192,1024] @ [1024,256] + b -> leaky -> H3[0]
  hipLaunchKernelGGL((k_gemm<1, bf16_t>), dim3(FAC / 128, Mrows / 128, 1), dim3(256), 0, stream,
                     CV, WPT + (size_t)3 * FAC * HID, BP + 3 * FAC, H3, (bf16_t*)nullptr, FAC, HID,
                     0LL, 0LL, 0LL, 0, 1.f, 1.f, 1.f);

  // tran o: [8192,256] @ [256,1024] + b -> d_out (fp32)
  hipLaunchKernelGGL((k_gemm<0, float>), dim3(HID / 128, Mrows / 128, 1), dim3(256), 0, stream,
                     H3, WTT + (size_t)3 * FAC * HID, BT + 3 * HID, (float*)d_out, (float*)nullptr, HID, FAC,
                     0LL, 0LL, 0LL, 0, 1.f, 1.f, 1.f);
}